// Round 10
// baseline (267.781 us; speedup 1.0000x reference)
//
#include <hip/hip_runtime.h>
#include <math.h>

// B=4, C=256 -> 4 groups x 64ch. H=W=128. img = g*4 + bb.
#define Hs 128
#define Ws 128
#define HWs 16384

typedef __attribute__((ext_vector_type(8))) short short8;
typedef __attribute__((ext_vector_type(8))) __bf16 bf16x8;
typedef __attribute__((ext_vector_type(4))) float f32x4;
typedef __attribute__((ext_vector_type(2))) float f32x2;

static __device__ __forceinline__ float bf2f(unsigned short u) {
    union { unsigned int i; float f; } v; v.i = ((unsigned int)u) << 16; return v.f;
}
// round-to-nearest-even fp32 -> bf16 (finite inputs)
static __device__ __forceinline__ unsigned short f2bf(float f) {
    unsigned int u = __builtin_bit_cast(unsigned int, f);
    return (unsigned short)((u + 0x7fffu + ((u >> 16) & 1u)) >> 16);
}
static __device__ __forceinline__ f32x4 mfma16(short8 a, short8 b, f32x4 c) {
    return __builtin_amdgcn_mfma_f32_16x16x32_bf16(
        __builtin_bit_cast(bf16x8, a), __builtin_bit_cast(bf16x8, b), c, 0, 0, 0);
}
// packed 2xf32 ops (VOP3P)
static __device__ __forceinline__ f32x2 pk_mul(f32x2 a, f32x2 b) {
    f32x2 d;
    asm("v_pk_mul_f32 %0, %1, %2" : "=v"(d) : "v"(a), "v"(b));
    return d;
}
static __device__ __forceinline__ f32x2 pk_fma(f32x2 a, f32x2 b, f32x2 c) {
    f32x2 d;
    asm("v_pk_fma_f32 %0, %1, %2, %3" : "=v"(d) : "v"(a), "v"(b), "v"(c));
    return d;
}
// single-instruction RNE pack of two f32 -> bf16x2 (== f2bf pair bit-exactly)
static __device__ __forceinline__ unsigned int cvt_pk_bf16(float lo, float hi) {
    unsigned int d;
    asm("v_cvt_pk_bf16_f32 %0, %1, %2" : "=v"(d) : "v"(lo), "v"(hi));
    return d;
}
// dword of 2 packed bf16 -> f32x2 {lo, hi}
static __device__ __forceinline__ f32x2 bfpair(unsigned int u) {
    union { unsigned int i[2]; f32x2 f; } v;
    v.i[0] = u << 16;
    v.i[1] = u & 0xffff0000u;
    return v.f;
}
// Workgroup barrier WITHOUT the vmcnt(0) drain __syncthreads() emits.
static __device__ __forceinline__ void barrier_lds_only() {
    asm volatile("s_waitcnt lgkmcnt(0)\n\ts_barrier" ::: "memory");
}

// ---------------------------------------------------------------------------
// k_xt: x [bb][256ch][H][W] fp32 -> xT [img][H*W pixel][64 c] bf16
// (channel-last), with weight-prep fused into the first 576 blocks.
// (byte-identical to R6)
// ---------------------------------------------------------------------------
__global__ __launch_bounds__(256) void k_xt(const float* __restrict__ x,
                                            const float* __restrict__ w,
                                            const float* __restrict__ b,
                                            const float* __restrict__ w_om,
                                            const float* __restrict__ gamma,
                                            const float* __restrict__ beta,
                                            const float* __restrict__ mean,
                                            const float* __restrict__ var,
                                            unsigned short* __restrict__ xT,
                                            unsigned short* __restrict__ w2,
                                            unsigned short* __restrict__ wom2,
                                            float* __restrict__ scsh) {
    const int tid = threadIdx.x;
    const int f = blockIdx.y * 256 + blockIdx.x;
    // ---- fused prep (first 576 flat blocks) ----
    if (f < 576) {
        int idx = f * 256 + tid;
        if (idx < 4 * 64 * 576) {
            int go = idx / 576;
            int ck = idx - go * 576;
            int k = ck >> 6, c = ck & 63;
            w2[idx] = f2bf(w[go * 576 + c * 9 + k]);
        }
        if (idx < 4 * 32 * 576) {
            int gj = idx / 576;
            int g = gj >> 5, j = gj & 31;
            int ck = idx - gj * 576;
            int k = ck >> 6, c = ck & 63;
            float v = (j < 27) ? w_om[(g * 27 + j) * 576 + c * 9 + k] : 0.f;
            wom2[idx] = f2bf(v);
        }
        if (idx < 256) {
            float sc = gamma[idx] * rsqrtf(var[idx] + 1e-5f);
            scsh[idx] = sc;
            scsh[256 + idx] = (b[idx] - mean[idx]) * sc + beta[idx];
        }
    }

    // ---- transpose/convert ----
    const int img = blockIdx.y;
    const int g = img >> 2, bb = img & 3;
    const int p0 = blockIdx.x * 64;
    __shared__ float t[64 * 65];

    const float* xg = x + (size_t)(bb * 256 + g * 64) * HWs + p0;
    const int l16 = tid & 15, grp = tid >> 4;
    float4 vv[4];
#pragma unroll
    for (int pass = 0; pass < 4; ++pass) {
        int c = pass * 16 + grp;
        vv[pass] = *(const float4*)(xg + (size_t)c * HWs + l16 * 4);
    }
#pragma unroll
    for (int pass = 0; pass < 4; ++pass) {
        int c = pass * 16 + grp;
        float* tr = &t[c * 65 + l16 * 4];
        tr[0] = vv[pass].x; tr[1] = vv[pass].y; tr[2] = vv[pass].z; tr[3] = vv[pass].w;
    }
    __syncthreads();
    const int p = tid >> 2, c16 = (tid & 3) * 16;
    unsigned short* dst = xT + (size_t)img * HWs * 64 + (size_t)(p0 + p) * 64 + c16;
    unsigned int rr[8];
#pragma unroll
    for (int q = 0; q < 8; ++q)
        rr[q] = cvt_pk_bf16(t[(c16 + 2 * q) * 65 + p], t[(c16 + 2 * q + 1) * 65 + p]);
    *(uint4*)dst       = make_uint4(rr[0], rr[1], rr[2], rr[3]);
    *(uint4*)(dst + 8) = make_uint4(rr[4], rr[5], rr[6], rr[7]);
}

// ---------------------------------------------------------------------------
// Offset/mask conv as bf16 MFMA GEMM, row-based LDS reuse.
// (byte-identical to R6 — best measured k_off)
// ---------------------------------------------------------------------------
__global__ __launch_bounds__(256, 3) void k_off(const unsigned short* __restrict__ xT,
                                                const unsigned short* __restrict__ wom2,
                                                const float* __restrict__ b_om,
                                                float* __restrict__ om) {
    const int img = blockIdx.y;
    const int g = img >> 2;
    const int h = blockIdx.x;
    const int tid = threadIdx.x;
    const int lane = tid & 63, wv = tid >> 6;
    const int mt = wv & 1, nh = wv >> 1;
    const int m = lane & 15, q = lane >> 4;

    __shared__ unsigned short xrow[3 * 130 * 64];   // 49,920 B, XOR-swizzled

    const unsigned short* xTi = xT + (size_t)img * HWs * 64;

    // ---- batched branchless staging: 3*130*8 = 3120 vec-chunks, 13/thread ----
    uint4 stg[13];
#pragma unroll
    for (int u = 0; u < 13; ++u) {
        int i = tid + u * 256;
        int rr = i / 1040;
        int rem = i - rr * 1040;
        int px = rem >> 3, j = rem & 7;
        int gh = h + rr - 1, gw = px - 1;
        int cgh = min(max(gh, 0), Hs - 1), cgw = min(max(gw, 0), Ws - 1);
        uint4 v = *(const uint4*)(xTi + (size_t)(cgh * Ws + cgw) * 64 + j * 8);
        bool inb = (gh >= 0) && (gh < Hs) && (gw >= 0) && (gw < Ws);
        stg[u].x = inb ? v.x : 0u;
        stg[u].y = inb ? v.y : 0u;
        stg[u].z = inb ? v.z : 0u;
        stg[u].w = inb ? v.w : 0u;
    }
#pragma unroll
    for (int u = 0; u < 13; ++u) {
        int i = tid + u * 256;
        if (i < 3120) {
            int rr = i / 1040;
            int rem = i - rr * 1040;
            int px = rem >> 3, j = rem & 7;
            *(uint4*)&xrow[(rr * 130 + px) * 64 + (j ^ (px & 7)) * 8] = stg[u];
        }
    }

    short8 afrag[18];
    const unsigned short* wb = wom2 + (size_t)(g * 32 + mt * 16 + m) * 576 + q * 8;
#pragma unroll
    for (int t = 0; t < 18; ++t) afrag[t] = *(const short8*)(wb + t * 32);

    f32x4 acc[4];
#pragma unroll
    for (int t = 0; t < 4; ++t) acc[t] = (f32x4){0.f, 0.f, 0.f, 0.f};

    __syncthreads();

#pragma unroll
    for (int k = 0; k < 9; ++k) {
        const int ki = k / 3, kj = k - ki * 3;
#pragma unroll
        for (int s = 0; s < 2; ++s) {
#pragma unroll
            for (int t = 0; t < 4; ++t) {
                int px = (nh * 4 + t) * 16 + m + kj;   // halo-shifted column
                int gran = (s * 4 + q) ^ (px & 7);
                short8 bfrag = *(const short8*)&xrow[(ki * 130 + px) * 64 + gran * 8];
                acc[t] = mfma16(afrag[k * 2 + s], bfrag, acc[t]);
            }
        }
    }

    float* omi = om + (size_t)img * 27 * HWs + h * Ws;
#pragma unroll
    for (int t = 0; t < 4; ++t) {
#pragma unroll
        for (int r = 0; r < 4; ++r) {
            int j = mt * 16 + q * 4 + r;
            if (j < 27) {
                float v = acc[t][r] + b_om[g * 27 + j];
                if (j >= 18) v = 1.f / (1.f + __expf(-v));  // mask sigmoid
                omi[(size_t)j * HWs + (nh * 4 + t) * 16 + m] = v;
            }
        }
    }
}

// ---------------------------------------------------------------------------
// Deformable conv as bf16 MFMA GEMM + BN + SiLU.
// R10: 512 threads / 8 waves per block, SAME work per block. Each thread
// gathers ONE 16B chunk x 4 corners (gth[2][4] = 32 regs, was 64) and
// combines 4 dwords/tap (was 8); each wave computes a 16ch x 32px sub-tile
// (acc[2]). R9 evidence: occupancy stuck at ~38.5% independent of LDS and
// arch-VGPR -> binder is per-wave unified reg footprint (gth). Halving it
// doubles the residency ceiling (4 blocks x 8 waves = 32 waves/CU).
// Per-element FP ops, corner order, K order, val layout+swizzle preserved
// -> output bit-identical.
// ---------------------------------------------------------------------------
__global__ __launch_bounds__(512, 4) void k_def(const unsigned short* __restrict__ xT,
                                                const float* __restrict__ om,
                                                const unsigned short* __restrict__ w2,
                                                const float* __restrict__ scsh,
                                                float* __restrict__ out) {
    const int img = blockIdx.y;
    const int g = img >> 2, bb = img & 3;
    const int p0 = blockIdx.x * 64;
    const int tid = threadIdx.x;
    const int lane = tid & 63, wv = tid >> 6;    // 8 waves
    const int m = lane & 15, q = lane >> 4;
    const int wch = wv & 3;                      // wave's 16-ch tile
    const int ph  = wv >> 2;                     // wave's 32-px half

    __shared__ unsigned short pO[4][576];        // u16 pixel offsets (<16384)
    __shared__ float pW[4][576];
    __shared__ unsigned short val[2][64 * 64];   // swizzled, stride 64
    __shared__ float lsc[64], lsh[64];

    if (tid < 64) {
        lsc[tid] = scsh[g * 64 + tid];
        lsh[tid] = scsh[256 + g * 64 + tid];
    }

    // ---- Phase A: bilinear gather params per (k, pixel) ----
    const float* omg = om + (size_t)img * 27 * HWs;
    for (int idx = tid; idx < 576; idx += 512) {
        int k = idx >> 6, pp = idx & 63;
        int p = p0 + pp;
        int h = p >> 7, w = p & 127;
        float dy = omg[k * HWs + p];
        float dx = omg[(9 + k) * HWs + p];
        float mk = omg[(18 + k) * HWs + p];
        int ki = k / 3, kj = k - ki * 3;
        float py = (float)(h - 1 + ki) + dy;
        float px = (float)(w - 1 + kj) + dx;
        float fy = floorf(py), fx = floorf(px);
        float wy1 = py - fy, wx1 = px - fx;
        float wy0 = 1.f - wy1, wx0 = 1.f - wx1;
        int y0 = (int)fy, x0 = (int)fx, y1 = y0 + 1, x1 = x0 + 1;
        bool vy0 = (y0 >= 0) && (y0 < Hs), vy1 = (y1 >= 0) && (y1 < Hs);
        bool vx0 = (x0 >= 0) && (x0 < Ws), vx1 = (x1 >= 0) && (x1 < Ws);
        int cy0 = min(max(y0, 0), Hs - 1), cy1 = min(max(y1, 0), Hs - 1);
        int cx0 = min(max(x0, 0), Ws - 1), cx1 = min(max(x1, 0), Ws - 1);
        pO[0][idx] = (unsigned short)(cy0 * Ws + cx0);
        pO[1][idx] = (unsigned short)(cy0 * Ws + cx1);
        pO[2][idx] = (unsigned short)(cy1 * Ws + cx0);
        pO[3][idx] = (unsigned short)(cy1 * Ws + cx1);
        pW[0][idx] = (vy0 && vx0) ? wy0 * wx0 * mk : 0.f;
        pW[1][idx] = (vy0 && vx1) ? wy0 * wx1 * mk : 0.f;
        pW[2][idx] = (vy1 && vx0) ? wy1 * wx0 * mk : 0.f;
        pW[3][idx] = (vy1 && vx1) ? wy1 * wx1 * mk : 0.f;
    }

    f32x4 acc[2];
#pragma unroll
    for (int t = 0; t < 2; ++t) acc[t] = (f32x4){0.f, 0.f, 0.f, 0.f};

    const unsigned short* xTi = xT + (size_t)img * HWs * 64;
    const int p = tid >> 3, j8 = tid & 7;        // pixel, 8-ch chunk
    const int wr_sw = ((p >> 1) & 7) << 3;       // write-side granule swizzle
    const int rd_sw = ((m >> 1) & 7) << 3;       // read-side

    __syncthreads();   // Phase A (and lsc/lsh) visible — full drain OK here

    // per-tap A-fragment double buffer
    short8 af[2][2];
    const unsigned short* wb = w2 + (size_t)(g * 64 + wch * 16 + m) * 576 + q * 8;
    auto fetchA = [&](int k, int bf) {
        af[bf][0] = *(const short8*)(wb + (k * 2 + 0) * 32);
        af[bf][1] = *(const short8*)(wb + (k * 2 + 1) * 32);
    };

    // double-buffered register gather prefetch: 4 corners x ONE 16B chunk
    uint4 gth[2][4];
    float wfb[2][4];
    auto fetch = [&](int k, int bf) {
        const int kb = k * 64 + p;
        const int off0 = pO[0][kb], off1 = pO[1][kb], off2 = pO[2][kb], off3 = pO[3][kb];
        wfb[bf][0] = pW[0][kb]; wfb[bf][1] = pW[1][kb];
        wfb[bf][2] = pW[2][kb]; wfb[bf][3] = pW[3][kb];
        gth[bf][0] = *(const uint4*)(xTi + (size_t)off0 * 64 + j8 * 8);
        gth[bf][1] = *(const uint4*)(xTi + (size_t)off1 * 64 + j8 * 8);
        gth[bf][2] = *(const uint4*)(xTi + (size_t)off2 * 64 + j8 * 8);
        gth[bf][3] = *(const uint4*)(xTi + (size_t)off3 * 64 + j8 * 8);
    };
    fetch(0, 0);
    fetchA(0, 0);

#pragma unroll
    for (int k = 0; k < 9; ++k) {
        const int cb = k & 1, nb = cb ^ 1;
        if (k < 8) {
            fetch(k + 1, nb);    // next tap's gathers in flight across barrier
            fetchA(k + 1, nb);
        }
        // ---- combine: packed 2xf32 math on prefetched regs ----
        unsigned short* vb = &val[cb][0];
        const float* wf = wfb[cb];
        f32x2 w0p = {wf[0], wf[0]}, w1p = {wf[1], wf[1]};
        f32x2 w2p = {wf[2], wf[2]}, w3p = {wf[3], wf[3]};
        unsigned int rr[4];
#pragma unroll
        for (int e = 0; e < 4; ++e) {
            f32x2 x0 = bfpair(((const unsigned int*)&gth[cb][0])[e]);
            f32x2 x1 = bfpair(((const unsigned int*)&gth[cb][1])[e]);
            f32x2 x2 = bfpair(((const unsigned int*)&gth[cb][2])[e]);
            f32x2 x3 = bfpair(((const unsigned int*)&gth[cb][3])[e]);
            f32x2 a = pk_mul(x0, w0p);
            a = pk_fma(x1, w1p, a);
            a = pk_fma(x2, w2p, a);
            a = pk_fma(x3, w3p, a);
            rr[e] = cvt_pk_bf16(a[0], a[1]);
        }
        *(uint4*)&vb[p * 64 + ((j8 << 3) ^ wr_sw)] = make_uint4(rr[0], rr[1], rr[2], rr[3]);
        barrier_lds_only();   // ds_writes visible; gathers STAY in flight
        // ---- Phase C: MFMA over this 64-wide K chunk (wave's 32-px half) ----
        const unsigned short* vr = &val[cb][0];
#pragma unroll
        for (int s = 0; s < 2; ++s) {
#pragma unroll
            for (int t = 0; t < 2; ++t) {
                const int row = ph * 32 + t * 16 + m;
                short8 bfrag = *(const short8*)&vr[row * 64 + ((s * 32 + q * 8) ^ rd_sw)];
                acc[t] = mfma16(af[cb][s], bfrag, acc[t]);
            }
        }
    }

    // ---- Epilogue: BN + SiLU, coalesced dword stores ----
    float* outg = out + ((size_t)bb * 256 + g * 64) * HWs + p0;
#pragma unroll
    for (int t = 0; t < 2; ++t) {
#pragma unroll
        for (int r = 0; r < 4; ++r) {
            int o = wch * 16 + q * 4 + r;
            float y = acc[t][r] * lsc[o] + lsh[o];
            outg[(size_t)o * HWs + ph * 32 + t * 16 + m] = y / (1.f + __expf(-y));
        }
    }
}

// ---------------------------------------------------------------------------
extern "C" void kernel_launch(void* const* d_in, const int* in_sizes, int n_in,
                              void* d_out, int out_size, void* d_ws, size_t ws_size,
                              hipStream_t stream) {
    const float* x     = (const float*)d_in[0];
    const float* w     = (const float*)d_in[1];
    const float* b     = (const float*)d_in[2];
    const float* w_om  = (const float*)d_in[3];
    const float* b_om  = (const float*)d_in[4];
    const float* gamma = (const float*)d_in[5];
    const float* beta  = (const float*)d_in[6];
    const float* mean  = (const float*)d_in[7];
    const float* var   = (const float*)d_in[8];
    float* out = (float*)d_out;

    char* ws = (char*)d_ws;
    float* om            = (float*)ws;                              // 28,311,552 B
    unsigned short* xT   = (unsigned short*)(ws + 28311552);        // 33,554,432 B
    unsigned short* w2   = (unsigned short*)(ws + 61865984);        //    294,912 B
    unsigned short* wom2 = (unsigned short*)(ws + 62160896);        //    147,456 B
    float* scsh          = (float*)(ws + 62308352);                 //      2,048 B

    hipLaunchKernelGGL(k_xt, dim3(256, 16), dim3(256), 0, stream,
                       x, w, b, w_om, gamma, beta, mean, var, xT, w2, wom2, scsh);
    hipLaunchKernelGGL(k_off, dim3(128, 16), dim3(256), 0, stream, xT, wom2, b_om, om);
    hipLaunchKernelGGL(k_def, dim3(256, 16), dim3(512), 0, stream, xT, om, w2, scsh, out);
}

// Round 11
// 244.786 us; speedup vs baseline: 1.0939x; 1.0939x over previous
//
#include <hip/hip_runtime.h>
#include <math.h>

// B=4, C=256 -> 4 groups x 64ch. H=W=128. img = g*4 + bb.
#define Hs 128
#define Ws 128
#define HWs 16384

typedef __attribute__((ext_vector_type(8))) short short8;
typedef __attribute__((ext_vector_type(8))) __bf16 bf16x8;
typedef __attribute__((ext_vector_type(4))) float f32x4;
typedef __attribute__((ext_vector_type(2))) float f32x2;

static __device__ __forceinline__ float bf2f(unsigned short u) {
    union { unsigned int i; float f; } v; v.i = ((unsigned int)u) << 16; return v.f;
}
// round-to-nearest-even fp32 -> bf16 (finite inputs)
static __device__ __forceinline__ unsigned short f2bf(float f) {
    unsigned int u = __builtin_bit_cast(unsigned int, f);
    return (unsigned short)((u + 0x7fffu + ((u >> 16) & 1u)) >> 16);
}
static __device__ __forceinline__ f32x4 mfma16(short8 a, short8 b, f32x4 c) {
    return __builtin_amdgcn_mfma_f32_16x16x32_bf16(
        __builtin_bit_cast(bf16x8, a), __builtin_bit_cast(bf16x8, b), c, 0, 0, 0);
}
// packed 2xf32 ops (VOP3P)
static __device__ __forceinline__ f32x2 pk_mul(f32x2 a, f32x2 b) {
    f32x2 d;
    asm("v_pk_mul_f32 %0, %1, %2" : "=v"(d) : "v"(a), "v"(b));
    return d;
}
static __device__ __forceinline__ f32x2 pk_fma(f32x2 a, f32x2 b, f32x2 c) {
    f32x2 d;
    asm("v_pk_fma_f32 %0, %1, %2, %3" : "=v"(d) : "v"(a), "v"(b), "v"(c));
    return d;
}
// single-instruction RNE pack of two f32 -> bf16x2 (== f2bf pair bit-exactly)
static __device__ __forceinline__ unsigned int cvt_pk_bf16(float lo, float hi) {
    unsigned int d;
    asm("v_cvt_pk_bf16_f32 %0, %1, %2" : "=v"(d) : "v"(lo), "v"(hi));
    return d;
}
// dword of 2 packed bf16 -> f32x2 {lo, hi}
static __device__ __forceinline__ f32x2 bfpair(unsigned int u) {
    union { unsigned int i[2]; f32x2 f; } v;
    v.i[0] = u << 16;
    v.i[1] = u & 0xffff0000u;
    return v.f;
}
// Workgroup barrier WITHOUT the vmcnt(0) drain __syncthreads() emits.
static __device__ __forceinline__ void barrier_lds_only() {
    asm volatile("s_waitcnt lgkmcnt(0)\n\ts_barrier" ::: "memory");
}

// ---------------------------------------------------------------------------
// k_xt: x [bb][256ch][H][W] fp32 -> xT [img][H*W pixel][64 c] bf16
// (channel-last), with weight-prep fused into the first 576 blocks.
//  w2  [g][64 o][576 ck2] bf16, ck2 = k*64+c
//  wom2[g][32 j][576 ck2] bf16 (j>=27 zero)
//  scsh[0..255]=gamma*rsqrt(var+eps); scsh[256..511]=(b-mean)*sc+beta
// (byte-identical to R6 — best measured)
// ---------------------------------------------------------------------------
__global__ __launch_bounds__(256) void k_xt(const float* __restrict__ x,
                                            const float* __restrict__ w,
                                            const float* __restrict__ b,
                                            const float* __restrict__ w_om,
                                            const float* __restrict__ gamma,
                                            const float* __restrict__ beta,
                                            const float* __restrict__ mean,
                                            const float* __restrict__ var,
                                            unsigned short* __restrict__ xT,
                                            unsigned short* __restrict__ w2,
                                            unsigned short* __restrict__ wom2,
                                            float* __restrict__ scsh) {
    const int tid = threadIdx.x;
    const int f = blockIdx.y * 256 + blockIdx.x;
    // ---- fused prep (first 576 flat blocks) ----
    if (f < 576) {
        int idx = f * 256 + tid;
        if (idx < 4 * 64 * 576) {
            int go = idx / 576;
            int ck = idx - go * 576;
            int k = ck >> 6, c = ck & 63;
            w2[idx] = f2bf(w[go * 576 + c * 9 + k]);
        }
        if (idx < 4 * 32 * 576) {
            int gj = idx / 576;
            int g = gj >> 5, j = gj & 31;
            int ck = idx - gj * 576;
            int k = ck >> 6, c = ck & 63;
            float v = (j < 27) ? w_om[(g * 27 + j) * 576 + c * 9 + k] : 0.f;
            wom2[idx] = f2bf(v);
        }
        if (idx < 256) {
            float sc = gamma[idx] * rsqrtf(var[idx] + 1e-5f);
            scsh[idx] = sc;
            scsh[256 + idx] = (b[idx] - mean[idx]) * sc + beta[idx];
        }
    }

    // ---- transpose/convert ----
    const int img = blockIdx.y;
    const int g = img >> 2, bb = img & 3;
    const int p0 = blockIdx.x * 64;
    __shared__ float t[64 * 65];

    const float* xg = x + (size_t)(bb * 256 + g * 64) * HWs + p0;
    const int l16 = tid & 15, grp = tid >> 4;
    float4 vv[4];
#pragma unroll
    for (int pass = 0; pass < 4; ++pass) {
        int c = pass * 16 + grp;
        vv[pass] = *(const float4*)(xg + (size_t)c * HWs + l16 * 4);
    }
#pragma unroll
    for (int pass = 0; pass < 4; ++pass) {
        int c = pass * 16 + grp;
        float* tr = &t[c * 65 + l16 * 4];
        tr[0] = vv[pass].x; tr[1] = vv[pass].y; tr[2] = vv[pass].z; tr[3] = vv[pass].w;
    }
    __syncthreads();
    const int p = tid >> 2, c16 = (tid & 3) * 16;
    unsigned short* dst = xT + (size_t)img * HWs * 64 + (size_t)(p0 + p) * 64 + c16;
    unsigned int rr[8];
#pragma unroll
    for (int q = 0; q < 8; ++q)
        rr[q] = cvt_pk_bf16(t[(c16 + 2 * q) * 65 + p], t[(c16 + 2 * q + 1) * 65 + p]);
    *(uint4*)dst       = make_uint4(rr[0], rr[1], rr[2], rr[3]);
    *(uint4*)(dst + 8) = make_uint4(rr[4], rr[5], rr[6], rr[7]);
}

// ---------------------------------------------------------------------------
// Offset/mask conv as bf16 MFMA GEMM, row-based LDS reuse.
// (byte-identical to R6 — best measured k_off)
// ---------------------------------------------------------------------------
__global__ __launch_bounds__(256, 3) void k_off(const unsigned short* __restrict__ xT,
                                                const unsigned short* __restrict__ wom2,
                                                const float* __restrict__ b_om,
                                                float* __restrict__ om) {
    const int img = blockIdx.y;
    const int g = img >> 2;
    const int h = blockIdx.x;
    const int tid = threadIdx.x;
    const int lane = tid & 63, wv = tid >> 6;
    const int mt = wv & 1, nh = wv >> 1;
    const int m = lane & 15, q = lane >> 4;

    __shared__ unsigned short xrow[3 * 130 * 64];   // 49,920 B, XOR-swizzled

    const unsigned short* xTi = xT + (size_t)img * HWs * 64;

    // ---- batched branchless staging: 3*130*8 = 3120 vec-chunks, 13/thread ----
    uint4 stg[13];
#pragma unroll
    for (int u = 0; u < 13; ++u) {
        int i = tid + u * 256;
        int rr = i / 1040;
        int rem = i - rr * 1040;
        int px = rem >> 3, j = rem & 7;
        int gh = h + rr - 1, gw = px - 1;
        int cgh = min(max(gh, 0), Hs - 1), cgw = min(max(gw, 0), Ws - 1);
        uint4 v = *(const uint4*)(xTi + (size_t)(cgh * Ws + cgw) * 64 + j * 8);
        bool inb = (gh >= 0) && (gh < Hs) && (gw >= 0) && (gw < Ws);
        stg[u].x = inb ? v.x : 0u;
        stg[u].y = inb ? v.y : 0u;
        stg[u].z = inb ? v.z : 0u;
        stg[u].w = inb ? v.w : 0u;
    }
#pragma unroll
    for (int u = 0; u < 13; ++u) {
        int i = tid + u * 256;
        if (i < 3120) {
            int rr = i / 1040;
            int rem = i - rr * 1040;
            int px = rem >> 3, j = rem & 7;
            *(uint4*)&xrow[(rr * 130 + px) * 64 + (j ^ (px & 7)) * 8] = stg[u];
        }
    }

    short8 afrag[18];
    const unsigned short* wb = wom2 + (size_t)(g * 32 + mt * 16 + m) * 576 + q * 8;
#pragma unroll
    for (int t = 0; t < 18; ++t) afrag[t] = *(const short8*)(wb + t * 32);

    f32x4 acc[4];
#pragma unroll
    for (int t = 0; t < 4; ++t) acc[t] = (f32x4){0.f, 0.f, 0.f, 0.f};

    __syncthreads();

#pragma unroll
    for (int k = 0; k < 9; ++k) {
        const int ki = k / 3, kj = k - ki * 3;
#pragma unroll
        for (int s = 0; s < 2; ++s) {
#pragma unroll
            for (int t = 0; t < 4; ++t) {
                int px = (nh * 4 + t) * 16 + m + kj;   // halo-shifted column
                int gran = (s * 4 + q) ^ (px & 7);
                short8 bfrag = *(const short8*)&xrow[(ki * 130 + px) * 64 + gran * 8];
                acc[t] = mfma16(afrag[k * 2 + s], bfrag, acc[t]);
            }
        }
    }

    float* omi = om + (size_t)img * 27 * HWs + h * Ws;
#pragma unroll
    for (int t = 0; t < 4; ++t) {
#pragma unroll
        for (int r = 0; r < 4; ++r) {
            int j = mt * 16 + q * 4 + r;
            if (j < 27) {
                float v = acc[t][r] + b_om[g * 27 + j];
                if (j >= 18) v = 1.f / (1.f + __expf(-v));  // mask sigmoid
                omi[(size_t)j * HWs + (nh * 4 + t) * 16 + m] = v;
            }
        }
    }
}

// ---------------------------------------------------------------------------
// Deformable conv as bf16 MFMA GEMM + BN + SiLU.
// R11: R6 structure (best measured: 4 waves, int pO, LDS 35,328) with ONE
// addition — s_setprio(1) around the MFMA cluster (T5). k_def CUs host 4
// INDEPENDENT blocks at different tap phases (not grid-lockstep), the
// regime where setprio measured positive (attn m191) vs lockstep null.
// R8/R9/R10 established: occupancy/ILP-depth/LDS are NOT the binder;
// this is the last zero-risk scheduling lever on the proven structure.
// ---------------------------------------------------------------------------
__global__ __launch_bounds__(256, 2) void k_def(const unsigned short* __restrict__ xT,
                                                const float* __restrict__ om,
                                                const unsigned short* __restrict__ w2,
                                                const float* __restrict__ scsh,
                                                float* __restrict__ out) {
    const int img = blockIdx.y;
    const int g = img >> 2, bb = img & 3;
    const int p0 = blockIdx.x * 64;
    const int tid = threadIdx.x;
    const int lane = tid & 63, wv = tid >> 6;
    const int m = lane & 15, q = lane >> 4;

    __shared__ int   pO[4][576];
    __shared__ float pW[4][576];
    __shared__ unsigned short val[2][64 * 64];   // swizzled, stride 64
    __shared__ float lsc[64], lsh[64];

    if (tid < 64) {
        lsc[tid] = scsh[g * 64 + tid];
        lsh[tid] = scsh[256 + g * 64 + tid];
    }

    // ---- Phase A: bilinear gather params per (k, pixel) ----
    const float* omg = om + (size_t)img * 27 * HWs;
    for (int idx = tid; idx < 576; idx += 256) {
        int k = idx >> 6, pp = idx & 63;
        int p = p0 + pp;
        int h = p >> 7, w = p & 127;
        float dy = omg[k * HWs + p];
        float dx = omg[(9 + k) * HWs + p];
        float mk = omg[(18 + k) * HWs + p];
        int ki = k / 3, kj = k - ki * 3;
        float py = (float)(h - 1 + ki) + dy;
        float px = (float)(w - 1 + kj) + dx;
        float fy = floorf(py), fx = floorf(px);
        float wy1 = py - fy, wx1 = px - fx;
        float wy0 = 1.f - wy1, wx0 = 1.f - wx1;
        int y0 = (int)fy, x0 = (int)fx, y1 = y0 + 1, x1 = x0 + 1;
        bool vy0 = (y0 >= 0) && (y0 < Hs), vy1 = (y1 >= 0) && (y1 < Hs);
        bool vx0 = (x0 >= 0) && (x0 < Ws), vx1 = (x1 >= 0) && (x1 < Ws);
        int cy0 = min(max(y0, 0), Hs - 1), cy1 = min(max(y1, 0), Hs - 1);
        int cx0 = min(max(x0, 0), Ws - 1), cx1 = min(max(x1, 0), Ws - 1);
        pO[0][idx] = cy0 * Ws + cx0;
        pO[1][idx] = cy0 * Ws + cx1;
        pO[2][idx] = cy1 * Ws + cx0;
        pO[3][idx] = cy1 * Ws + cx1;
        pW[0][idx] = (vy0 && vx0) ? wy0 * wx0 * mk : 0.f;
        pW[1][idx] = (vy0 && vx1) ? wy0 * wx1 * mk : 0.f;
        pW[2][idx] = (vy1 && vx0) ? wy1 * wx0 * mk : 0.f;
        pW[3][idx] = (vy1 && vx1) ? wy1 * wx1 * mk : 0.f;
    }

    f32x4 acc[4];
#pragma unroll
    for (int t = 0; t < 4; ++t) acc[t] = (f32x4){0.f, 0.f, 0.f, 0.f};

    const unsigned short* xTi = xT + (size_t)img * HWs * 64;
    const int p = tid >> 2, c4 = tid & 3;
    const int wr_sw = ((p >> 1) & 7) << 3;       // write-side granule swizzle
    const int rd_sw = ((m >> 1) & 7) << 3;       // read-side (row = t*16+m)

    __syncthreads();   // Phase A (and lsc/lsh) visible — full drain OK here

    // per-tap A-fragment double buffer (2 x short8 = 8 VGPRs per buffer)
    short8 af[2][2];
    const unsigned short* wb = w2 + (size_t)(g * 64 + wv * 16 + m) * 576 + q * 8;
    auto fetchA = [&](int k, int bf) {
        af[bf][0] = *(const short8*)(wb + (k * 2 + 0) * 32);
        af[bf][1] = *(const short8*)(wb + (k * 2 + 1) * 32);
    };

    // double-buffered register gather prefetch:
    // 8 chunks = 4 corners x 2 adjacent 8-ch chunks {2*c4, 2*c4+1}
    uint4 gth[2][8];
    float wfb[2][4];
    auto fetch = [&](int k, int bf) {
        const int kb = k * 64 + p;
        const int off0 = pO[0][kb], off1 = pO[1][kb], off2 = pO[2][kb], off3 = pO[3][kb];
        wfb[bf][0] = pW[0][kb]; wfb[bf][1] = pW[1][kb];
        wfb[bf][2] = pW[2][kb]; wfb[bf][3] = pW[3][kb];
        const unsigned short* s0 = xTi + (size_t)off0 * 64 + c4 * 16;
        const unsigned short* s1 = xTi + (size_t)off1 * 64 + c4 * 16;
        const unsigned short* s2 = xTi + (size_t)off2 * 64 + c4 * 16;
        const unsigned short* s3 = xTi + (size_t)off3 * 64 + c4 * 16;
        gth[bf][0] = *(const uint4*)(s0);
        gth[bf][1] = *(const uint4*)(s1);
        gth[bf][2] = *(const uint4*)(s2);
        gth[bf][3] = *(const uint4*)(s3);
        gth[bf][4] = *(const uint4*)(s0 + 8);
        gth[bf][5] = *(const uint4*)(s1 + 8);
        gth[bf][6] = *(const uint4*)(s2 + 8);
        gth[bf][7] = *(const uint4*)(s3 + 8);
    };
    fetch(0, 0);
    fetchA(0, 0);

#pragma unroll
    for (int k = 0; k < 9; ++k) {
        const int cb = k & 1, nb = cb ^ 1;
        if (k < 8) {
            fetch(k + 1, nb);    // next tap's gathers in flight across barrier
            fetchA(k + 1, nb);   // next tap's A-fragments too
        }
        // ---- combine: packed 2xf32 math on prefetched regs ----
        unsigned short* vb = &val[cb][0];
        const float* wf = wfb[cb];
        f32x2 w0p = {wf[0], wf[0]}, w1p = {wf[1], wf[1]};
        f32x2 w2p = {wf[2], wf[2]}, w3p = {wf[3], wf[3]};
#pragma unroll
        for (int it = 0; it < 2; ++it) {
            const int oc8 = (2 * c4 + it) * 8;
            unsigned int rr[4];
#pragma unroll
            for (int e = 0; e < 4; ++e) {
                f32x2 x0 = bfpair(((const unsigned int*)&gth[cb][it * 4 + 0])[e]);
                f32x2 x1 = bfpair(((const unsigned int*)&gth[cb][it * 4 + 1])[e]);
                f32x2 x2 = bfpair(((const unsigned int*)&gth[cb][it * 4 + 2])[e]);
                f32x2 x3 = bfpair(((const unsigned int*)&gth[cb][it * 4 + 3])[e]);
                f32x2 a = pk_mul(x0, w0p);
                a = pk_fma(x1, w1p, a);
                a = pk_fma(x2, w2p, a);
                a = pk_fma(x3, w3p, a);
                rr[e] = cvt_pk_bf16(a[0], a[1]);
            }
            *(uint4*)&vb[p * 64 + (oc8 ^ wr_sw)] = make_uint4(rr[0], rr[1], rr[2], rr[3]);
        }
        barrier_lds_only();   // ds_writes visible; gathers STAY in flight
        // ---- Phase C: MFMA over this 64-wide K chunk (setprio-wrapped) ----
        const unsigned short* vr = &val[cb][0];
        __builtin_amdgcn_s_setprio(1);
#pragma unroll
        for (int s = 0; s < 2; ++s) {
#pragma unroll
            for (int t = 0; t < 4; ++t) {
                const int row = t * 16 + m;
                short8 bfrag = *(const short8*)&vr[row * 64 + ((s * 32 + q * 8) ^ rd_sw)];
                acc[t] = mfma16(af[cb][s], bfrag, acc[t]);
            }
        }
        __builtin_amdgcn_s_setprio(0);
    }

    // ---- Epilogue: BN + SiLU, coalesced dword stores ----
    float* outg = out + ((size_t)bb * 256 + g * 64) * HWs + p0;
#pragma unroll
    for (int t = 0; t < 4; ++t) {
#pragma unroll
        for (int r = 0; r < 4; ++r) {
            int o = wv * 16 + q * 4 + r;
            float y = acc[t][r] * lsc[o] + lsh[o];
            outg[(size_t)o * HWs + t * 16 + m] = y / (1.f + __expf(-y));
        }
    }
}

// ---------------------------------------------------------------------------
extern "C" void kernel_launch(void* const* d_in, const int* in_sizes, int n_in,
                              void* d_out, int out_size, void* d_ws, size_t ws_size,
                              hipStream_t stream) {
    const float* x     = (const float*)d_in[0];
    const float* w     = (const float*)d_in[1];
    const float* b     = (const float*)d_in[2];
    const float* w_om  = (const float*)d_in[3];
    const float* b_om  = (const float*)d_in[4];
    const float* gamma = (const float*)d_in[5];
    const float* beta  = (const float*)d_in[6];
    const float* mean  = (const float*)d_in[7];
    const float* var   = (const float*)d_in[8];
    float* out = (float*)d_out;

    char* ws = (char*)d_ws;
    float* om            = (float*)ws;                              // 28,311,552 B
    unsigned short* xT   = (unsigned short*)(ws + 28311552);        // 33,554,432 B
    unsigned short* w2   = (unsigned short*)(ws + 61865984);        //    294,912 B
    unsigned short* wom2 = (unsigned short*)(ws + 62160896);        //    147,456 B
    float* scsh          = (float*)(ws + 62308352);                 //      2,048 B

    hipLaunchKernelGGL(k_xt, dim3(256, 16), dim3(256), 0, stream,
                       x, w, b, w_om, gamma, beta, mean, var, xT, w2, wom2, scsh);
    hipLaunchKernelGGL(k_off, dim3(128, 16), dim3(256), 0, stream, xT, wom2, b_om, om);
    hipLaunchKernelGGL(k_def, dim3(256, 16), dim3(256), 0, stream, xT, om, w2, scsh, out);
}

// Round 12
// 239.270 us; speedup vs baseline: 1.1192x; 1.0231x over previous
//
#include <hip/hip_runtime.h>
#include <math.h>

// B=4, C=256 -> 4 groups x 64ch. H=W=128. img = g*4 + bb.
#define Hs 128
#define Ws 128
#define HWs 16384

typedef __attribute__((ext_vector_type(8))) short short8;
typedef __attribute__((ext_vector_type(8))) __bf16 bf16x8;
typedef __attribute__((ext_vector_type(4))) float f32x4;
typedef __attribute__((ext_vector_type(2))) float f32x2;

static __device__ __forceinline__ float bf2f(unsigned short u) {
    union { unsigned int i; float f; } v; v.i = ((unsigned int)u) << 16; return v.f;
}
// round-to-nearest-even fp32 -> bf16 (finite inputs)
static __device__ __forceinline__ unsigned short f2bf(float f) {
    unsigned int u = __builtin_bit_cast(unsigned int, f);
    return (unsigned short)((u + 0x7fffu + ((u >> 16) & 1u)) >> 16);
}
static __device__ __forceinline__ f32x4 mfma16(short8 a, short8 b, f32x4 c) {
    return __builtin_amdgcn_mfma_f32_16x16x32_bf16(
        __builtin_bit_cast(bf16x8, a), __builtin_bit_cast(bf16x8, b), c, 0, 0, 0);
}
// packed 2xf32 ops (VOP3P)
static __device__ __forceinline__ f32x2 pk_mul(f32x2 a, f32x2 b) {
    f32x2 d;
    asm("v_pk_mul_f32 %0, %1, %2" : "=v"(d) : "v"(a), "v"(b));
    return d;
}
static __device__ __forceinline__ f32x2 pk_fma(f32x2 a, f32x2 b, f32x2 c) {
    f32x2 d;
    asm("v_pk_fma_f32 %0, %1, %2, %3" : "=v"(d) : "v"(a), "v"(b), "v"(c));
    return d;
}
// single-instruction RNE pack of two f32 -> bf16x2 (== f2bf pair bit-exactly)
static __device__ __forceinline__ unsigned int cvt_pk_bf16(float lo, float hi) {
    unsigned int d;
    asm("v_cvt_pk_bf16_f32 %0, %1, %2" : "=v"(d) : "v"(lo), "v"(hi));
    return d;
}
// dword of 2 packed bf16 -> f32x2 {lo, hi}
static __device__ __forceinline__ f32x2 bfpair(unsigned int u) {
    union { unsigned int i[2]; f32x2 f; } v;
    v.i[0] = u << 16;
    v.i[1] = u & 0xffff0000u;
    return v.f;
}
// Workgroup barrier WITHOUT the vmcnt(0) drain __syncthreads() emits.
static __device__ __forceinline__ void barrier_lds_only() {
    asm volatile("s_waitcnt lgkmcnt(0)\n\ts_barrier" ::: "memory");
}

// ---------------------------------------------------------------------------
// k_xt: x [bb][256ch][H][W] fp32 -> xT [img][H*W pixel][64 c] bf16
// (channel-last), with weight-prep fused into the first 576 blocks.
//  w2  [g][64 o][576 ck2] bf16, ck2 = k*64+c
//  wom2[g][32 j][576 ck2] bf16 (j>=27 zero)
//  scsh[0..255]=gamma*rsqrt(var+eps); scsh[256..511]=(b-mean)*sc+beta
// (byte-identical to R6 — session-best configuration)
// ---------------------------------------------------------------------------
__global__ __launch_bounds__(256) void k_xt(const float* __restrict__ x,
                                            const float* __restrict__ w,
                                            const float* __restrict__ b,
                                            const float* __restrict__ w_om,
                                            const float* __restrict__ gamma,
                                            const float* __restrict__ beta,
                                            const float* __restrict__ mean,
                                            const float* __restrict__ var,
                                            unsigned short* __restrict__ xT,
                                            unsigned short* __restrict__ w2,
                                            unsigned short* __restrict__ wom2,
                                            float* __restrict__ scsh) {
    const int tid = threadIdx.x;
    const int f = blockIdx.y * 256 + blockIdx.x;
    // ---- fused prep (first 576 flat blocks) ----
    if (f < 576) {
        int idx = f * 256 + tid;
        if (idx < 4 * 64 * 576) {
            int go = idx / 576;
            int ck = idx - go * 576;
            int k = ck >> 6, c = ck & 63;
            w2[idx] = f2bf(w[go * 576 + c * 9 + k]);
        }
        if (idx < 4 * 32 * 576) {
            int gj = idx / 576;
            int g = gj >> 5, j = gj & 31;
            int ck = idx - gj * 576;
            int k = ck >> 6, c = ck & 63;
            float v = (j < 27) ? w_om[(g * 27 + j) * 576 + c * 9 + k] : 0.f;
            wom2[idx] = f2bf(v);
        }
        if (idx < 256) {
            float sc = gamma[idx] * rsqrtf(var[idx] + 1e-5f);
            scsh[idx] = sc;
            scsh[256 + idx] = (b[idx] - mean[idx]) * sc + beta[idx];
        }
    }

    // ---- transpose/convert ----
    const int img = blockIdx.y;
    const int g = img >> 2, bb = img & 3;
    const int p0 = blockIdx.x * 64;
    __shared__ float t[64 * 65];

    const float* xg = x + (size_t)(bb * 256 + g * 64) * HWs + p0;
    const int l16 = tid & 15, grp = tid >> 4;
    float4 vv[4];
#pragma unroll
    for (int pass = 0; pass < 4; ++pass) {
        int c = pass * 16 + grp;
        vv[pass] = *(const float4*)(xg + (size_t)c * HWs + l16 * 4);
    }
#pragma unroll
    for (int pass = 0; pass < 4; ++pass) {
        int c = pass * 16 + grp;
        float* tr = &t[c * 65 + l16 * 4];
        tr[0] = vv[pass].x; tr[1] = vv[pass].y; tr[2] = vv[pass].z; tr[3] = vv[pass].w;
    }
    __syncthreads();
    const int p = tid >> 2, c16 = (tid & 3) * 16;
    unsigned short* dst = xT + (size_t)img * HWs * 64 + (size_t)(p0 + p) * 64 + c16;
    unsigned int rr[8];
#pragma unroll
    for (int q = 0; q < 8; ++q)
        rr[q] = cvt_pk_bf16(t[(c16 + 2 * q) * 65 + p], t[(c16 + 2 * q + 1) * 65 + p]);
    *(uint4*)dst       = make_uint4(rr[0], rr[1], rr[2], rr[3]);
    *(uint4*)(dst + 8) = make_uint4(rr[4], rr[5], rr[6], rr[7]);
}

// ---------------------------------------------------------------------------
// Offset/mask conv as bf16 MFMA GEMM, row-based LDS reuse.
// Batched branchless staging (13 clamped loads -> regs -> LDS, one vmcnt
// chain), stride-64 + granule XOR swizzle, 49,920 B LDS, 3 blocks/CU.
// (byte-identical to R6 — best measured k_off)
// ---------------------------------------------------------------------------
__global__ __launch_bounds__(256, 3) void k_off(const unsigned short* __restrict__ xT,
                                                const unsigned short* __restrict__ wom2,
                                                const float* __restrict__ b_om,
                                                float* __restrict__ om) {
    const int img = blockIdx.y;
    const int g = img >> 2;
    const int h = blockIdx.x;
    const int tid = threadIdx.x;
    const int lane = tid & 63, wv = tid >> 6;
    const int mt = wv & 1, nh = wv >> 1;
    const int m = lane & 15, q = lane >> 4;

    __shared__ unsigned short xrow[3 * 130 * 64];   // 49,920 B, XOR-swizzled

    const unsigned short* xTi = xT + (size_t)img * HWs * 64;

    // ---- batched branchless staging: 3*130*8 = 3120 vec-chunks, 13/thread ----
    uint4 stg[13];
#pragma unroll
    for (int u = 0; u < 13; ++u) {
        int i = tid + u * 256;
        int rr = i / 1040;
        int rem = i - rr * 1040;
        int px = rem >> 3, j = rem & 7;
        int gh = h + rr - 1, gw = px - 1;
        int cgh = min(max(gh, 0), Hs - 1), cgw = min(max(gw, 0), Ws - 1);
        uint4 v = *(const uint4*)(xTi + (size_t)(cgh * Ws + cgw) * 64 + j * 8);
        bool inb = (gh >= 0) && (gh < Hs) && (gw >= 0) && (gw < Ws);
        stg[u].x = inb ? v.x : 0u;
        stg[u].y = inb ? v.y : 0u;
        stg[u].z = inb ? v.z : 0u;
        stg[u].w = inb ? v.w : 0u;
    }
#pragma unroll
    for (int u = 0; u < 13; ++u) {
        int i = tid + u * 256;
        if (i < 3120) {
            int rr = i / 1040;
            int rem = i - rr * 1040;
            int px = rem >> 3, j = rem & 7;
            *(uint4*)&xrow[(rr * 130 + px) * 64 + (j ^ (px & 7)) * 8] = stg[u];
        }
    }

    short8 afrag[18];
    const unsigned short* wb = wom2 + (size_t)(g * 32 + mt * 16 + m) * 576 + q * 8;
#pragma unroll
    for (int t = 0; t < 18; ++t) afrag[t] = *(const short8*)(wb + t * 32);

    f32x4 acc[4];
#pragma unroll
    for (int t = 0; t < 4; ++t) acc[t] = (f32x4){0.f, 0.f, 0.f, 0.f};

    __syncthreads();

#pragma unroll
    for (int k = 0; k < 9; ++k) {
        const int ki = k / 3, kj = k - ki * 3;
#pragma unroll
        for (int s = 0; s < 2; ++s) {
#pragma unroll
            for (int t = 0; t < 4; ++t) {
                int px = (nh * 4 + t) * 16 + m + kj;   // halo-shifted column
                int gran = (s * 4 + q) ^ (px & 7);
                short8 bfrag = *(const short8*)&xrow[(ki * 130 + px) * 64 + gran * 8];
                acc[t] = mfma16(afrag[k * 2 + s], bfrag, acc[t]);
            }
        }
    }

    float* omi = om + (size_t)img * 27 * HWs + h * Ws;
#pragma unroll
    for (int t = 0; t < 4; ++t) {
#pragma unroll
        for (int r = 0; r < 4; ++r) {
            int j = mt * 16 + q * 4 + r;
            if (j < 27) {
                float v = acc[t][r] + b_om[g * 27 + j];
                if (j >= 18) v = 1.f / (1.f + __expf(-v));  // mask sigmoid
                omi[(size_t)j * HWs + (nh * 4 + t) * 16 + m] = v;
            }
        }
    }
}

// ---------------------------------------------------------------------------
// Deformable conv as bf16 MFMA GEMM + BN + SiLU.
// R6 structure restored exactly (session best, 240.2 µs total, k_def 90.5):
// 4 waves, double-buffered gather+A-frag prefetch, lgkmcnt-only barrier,
// XOR-swizzled val, pk_mul/pk_fma+cvt_pk combine, launch_bounds(256,2).
// Probed and rejected: vmcnt-draining barrier (R4 null), depth-2 prefetch
// (R8 -22%), u16 pO / 5 blocks-CU (R9 null), 8-wave split (R10 -33%),
// setprio (R11 -5%). This configuration is the measured local optimum.
// ---------------------------------------------------------------------------
__global__ __launch_bounds__(256, 2) void k_def(const unsigned short* __restrict__ xT,
                                                const float* __restrict__ om,
                                                const unsigned short* __restrict__ w2,
                                                const float* __restrict__ scsh,
                                                float* __restrict__ out) {
    const int img = blockIdx.y;
    const int g = img >> 2, bb = img & 3;
    const int p0 = blockIdx.x * 64;
    const int tid = threadIdx.x;
    const int lane = tid & 63, wv = tid >> 6;
    const int m = lane & 15, q = lane >> 4;

    __shared__ int   pO[4][576];
    __shared__ float pW[4][576];
    __shared__ unsigned short val[2][64 * 64];   // swizzled, stride 64
    __shared__ float lsc[64], lsh[64];

    if (tid < 64) {
        lsc[tid] = scsh[g * 64 + tid];
        lsh[tid] = scsh[256 + g * 64 + tid];
    }

    // ---- Phase A: bilinear gather params per (k, pixel) ----
    const float* omg = om + (size_t)img * 27 * HWs;
    for (int idx = tid; idx < 576; idx += 256) {
        int k = idx >> 6, pp = idx & 63;
        int p = p0 + pp;
        int h = p >> 7, w = p & 127;
        float dy = omg[k * HWs + p];
        float dx = omg[(9 + k) * HWs + p];
        float mk = omg[(18 + k) * HWs + p];
        int ki = k / 3, kj = k - ki * 3;
        float py = (float)(h - 1 + ki) + dy;
        float px = (float)(w - 1 + kj) + dx;
        float fy = floorf(py), fx = floorf(px);
        float wy1 = py - fy, wx1 = px - fx;
        float wy0 = 1.f - wy1, wx0 = 1.f - wx1;
        int y0 = (int)fy, x0 = (int)fx, y1 = y0 + 1, x1 = x0 + 1;
        bool vy0 = (y0 >= 0) && (y0 < Hs), vy1 = (y1 >= 0) && (y1 < Hs);
        bool vx0 = (x0 >= 0) && (x0 < Ws), vx1 = (x1 >= 0) && (x1 < Ws);
        int cy0 = min(max(y0, 0), Hs - 1), cy1 = min(max(y1, 0), Hs - 1);
        int cx0 = min(max(x0, 0), Ws - 1), cx1 = min(max(x1, 0), Ws - 1);
        pO[0][idx] = cy0 * Ws + cx0;
        pO[1][idx] = cy0 * Ws + cx1;
        pO[2][idx] = cy1 * Ws + cx0;
        pO[3][idx] = cy1 * Ws + cx1;
        pW[0][idx] = (vy0 && vx0) ? wy0 * wx0 * mk : 0.f;
        pW[1][idx] = (vy0 && vx1) ? wy0 * wx1 * mk : 0.f;
        pW[2][idx] = (vy1 && vx0) ? wy1 * wx0 * mk : 0.f;
        pW[3][idx] = (vy1 && vx1) ? wy1 * wx1 * mk : 0.f;
    }

    f32x4 acc[4];
#pragma unroll
    for (int t = 0; t < 4; ++t) acc[t] = (f32x4){0.f, 0.f, 0.f, 0.f};

    const unsigned short* xTi = xT + (size_t)img * HWs * 64;
    const int p = tid >> 2, c4 = tid & 3;
    const int wr_sw = ((p >> 1) & 7) << 3;       // write-side granule swizzle
    const int rd_sw = ((m >> 1) & 7) << 3;       // read-side (row = t*16+m)

    __syncthreads();   // Phase A (and lsc/lsh) visible — full drain OK here

    // per-tap A-fragment double buffer (2 x short8 = 8 VGPRs per buffer)
    short8 af[2][2];
    const unsigned short* wb = w2 + (size_t)(g * 64 + wv * 16 + m) * 576 + q * 8;
    auto fetchA = [&](int k, int bf) {
        af[bf][0] = *(const short8*)(wb + (k * 2 + 0) * 32);
        af[bf][1] = *(const short8*)(wb + (k * 2 + 1) * 32);
    };

    // double-buffered register gather prefetch:
    // 8 chunks = 4 corners x 2 adjacent 8-ch chunks {2*c4, 2*c4+1}
    uint4 gth[2][8];
    float wfb[2][4];
    auto fetch = [&](int k, int bf) {
        const int kb = k * 64 + p;
        const int off0 = pO[0][kb], off1 = pO[1][kb], off2 = pO[2][kb], off3 = pO[3][kb];
        wfb[bf][0] = pW[0][kb]; wfb[bf][1] = pW[1][kb];
        wfb[bf][2] = pW[2][kb]; wfb[bf][3] = pW[3][kb];
        const unsigned short* s0 = xTi + (size_t)off0 * 64 + c4 * 16;
        const unsigned short* s1 = xTi + (size_t)off1 * 64 + c4 * 16;
        const unsigned short* s2 = xTi + (size_t)off2 * 64 + c4 * 16;
        const unsigned short* s3 = xTi + (size_t)off3 * 64 + c4 * 16;
        gth[bf][0] = *(const uint4*)(s0);
        gth[bf][1] = *(const uint4*)(s1);
        gth[bf][2] = *(const uint4*)(s2);
        gth[bf][3] = *(const uint4*)(s3);
        gth[bf][4] = *(const uint4*)(s0 + 8);
        gth[bf][5] = *(const uint4*)(s1 + 8);
        gth[bf][6] = *(const uint4*)(s2 + 8);
        gth[bf][7] = *(const uint4*)(s3 + 8);
    };
    fetch(0, 0);
    fetchA(0, 0);

#pragma unroll
    for (int k = 0; k < 9; ++k) {
        const int cb = k & 1, nb = cb ^ 1;
        if (k < 8) {
            fetch(k + 1, nb);    // next tap's gathers in flight across barrier
            fetchA(k + 1, nb);   // next tap's A-fragments too
        }
        // ---- combine: packed 2xf32 math on prefetched regs ----
        unsigned short* vb = &val[cb][0];
        const float* wf = wfb[cb];
        f32x2 w0p = {wf[0], wf[0]}, w1p = {wf[1], wf[1]};
        f32x2 w2p = {wf[2], wf[2]}, w3p = {wf[3], wf[3]};
#pragma unroll
        for (int it = 0; it < 2; ++it) {
            const int oc8 = (2 * c4 + it) * 8;
            unsigned int rr[4];
#pragma unroll
            for (int e = 0; e < 4; ++e) {
                f32x2 x0 = bfpair(((const unsigned int*)&gth[cb][it * 4 + 0])[e]);
                f32x2 x1 = bfpair(((const unsigned int*)&gth[cb][it * 4 + 1])[e]);
                f32x2 x2 = bfpair(((const unsigned int*)&gth[cb][it * 4 + 2])[e]);
                f32x2 x3 = bfpair(((const unsigned int*)&gth[cb][it * 4 + 3])[e]);
                f32x2 a = pk_mul(x0, w0p);
                a = pk_fma(x1, w1p, a);
                a = pk_fma(x2, w2p, a);
                a = pk_fma(x3, w3p, a);
                rr[e] = cvt_pk_bf16(a[0], a[1]);
            }
            *(uint4*)&vb[p * 64 + (oc8 ^ wr_sw)] = make_uint4(rr[0], rr[1], rr[2], rr[3]);
        }
        barrier_lds_only();   // ds_writes visible; gathers STAY in flight
        // ---- Phase C: MFMA over this 64-wide K chunk ----
        const unsigned short* vr = &val[cb][0];
#pragma unroll
        for (int s = 0; s < 2; ++s) {
#pragma unroll
            for (int t = 0; t < 4; ++t) {
                const int row = t * 16 + m;
                short8 bfrag = *(const short8*)&vr[row * 64 + ((s * 32 + q * 8) ^ rd_sw)];
                acc[t] = mfma16(af[cb][s], bfrag, acc[t]);
            }
        }
    }

    // ---- Epilogue: BN + SiLU, coalesced dword stores ----
    float* outg = out + ((size_t)bb * 256 + g * 64) * HWs + p0;
#pragma unroll
    for (int t = 0; t < 4; ++t) {
#pragma unroll
        for (int r = 0; r < 4; ++r) {
            int o = wv * 16 + q * 4 + r;
            float y = acc[t][r] * lsc[o] + lsh[o];
            outg[(size_t)o * HWs + t * 16 + m] = y / (1.f + __expf(-y));
        }
    }
}

// ---------------------------------------------------------------------------
extern "C" void kernel_launch(void* const* d_in, const int* in_sizes, int n_in,
                              void* d_out, int out_size, void* d_ws, size_t ws_size,
                              hipStream_t stream) {
    const float* x     = (const float*)d_in[0];
    const float* w     = (const float*)d_in[1];
    const float* b     = (const float*)d_in[2];
    const float* w_om  = (const float*)d_in[3];
    const float* b_om  = (const float*)d_in[4];
    const float* gamma = (const float*)d_in[5];
    const float* beta  = (const float*)d_in[6];
    const float* mean  = (const float*)d_in[7];
    const float* var   = (const float*)d_in[8];
    float* out = (float*)d_out;

    char* ws = (char*)d_ws;
    float* om            = (float*)ws;                              // 28,311,552 B
    unsigned short* xT   = (unsigned short*)(ws + 28311552);        // 33,554,432 B
    unsigned short* w2   = (unsigned short*)(ws + 61865984);        //    294,912 B
    unsigned short* wom2 = (unsigned short*)(ws + 62160896);        //    147,456 B
    float* scsh          = (float*)(ws + 62308352);                 //      2,048 B

    hipLaunchKernelGGL(k_xt, dim3(256, 16), dim3(256), 0, stream,
                       x, w, b, w_om, gamma, beta, mean, var, xT, w2, wom2, scsh);
    hipLaunchKernelGGL(k_off, dim3(128, 16), dim3(256), 0, stream, xT, wom2, b_om, om);
    hipLaunchKernelGGL(k_def, dim3(256, 16), dim3(256), 0, stream, xT, om, w2, scsh, out);
}